// Round 3
// baseline (86.948 us; speedup 1.0000x reference)
//
#include <hip/hip_runtime.h>
#include <math.h>

#define B_    256
#define I_    128
#define O_    256
#define D_    33
#define NSUM  100
#define NPROD 10
#define A_SUP 1.5f
#define PI_F  3.14159265358979323846f

#define ICHUNK 32                      // i's per block
#define NCHUNK (I_ / ICHUNK)           // 4 blocks per batch row

// ---------------------------------------------------------------------------
// Prep: transpose W[i][o][d] -> Wt[i][d][o] so per-(i, d-window) reads in the
// main kernel are contiguous & coalesced across o. One block per i.
// LDS reads ld[o*33+d]: stride 33 mod 32 == 1 -> conflict-free.
// ---------------------------------------------------------------------------
__global__ __launch_bounds__(256) void transpose_w(const float* __restrict__ W,
                                                   float* __restrict__ Wt) {
    const int i = blockIdx.x;
    __shared__ float ld[O_ * D_];                 // 33 KiB
    const float* src = W + (size_t)i * O_ * D_;
    for (int t = threadIdx.x; t < O_ * D_; t += blockDim.x)
        ld[t] = src[t];
    __syncthreads();
    float* dst = Wt + (size_t)i * D_ * O_;
    for (int t = threadIdx.x; t < D_ * O_; t += blockDim.x) {
        const int d = t >> 8;                     // t / 256
        const int o = t & (O_ - 1);               // t % 256
        dst[t] = ld[o * D_ + d];
    }
}

// ---------------------------------------------------------------------------
// Main: grid = B * NCHUNK. Block (b, chunk) handles ICHUNK i's for row b.
// Phase A: sparse basis (ICHUNK i x 4 d window) via Chebyshev cos recurrence.
// Phase B: partial y[b,o] over this i-chunk, coalesced reads of Wt, then one
// fp32 atomicAdd per o into d_out (zeroed beforehand).
// ---------------------------------------------------------------------------
__global__ __launch_bounds__(512, 4) void kan_main(const float* __restrict__ x,
                                                   const float* __restrict__ Wt,
                                                   const float* __restrict__ comp,
                                                   const float* __restrict__ cen,
                                                   float* __restrict__ y) {
    const int b     = blockIdx.x >> 2;            // blockIdx.x / NCHUNK
    const int chunk = blockIdx.x & (NCHUNK - 1);
    const int i0    = chunk * ICHUNK;
    const int tid   = threadIdx.x;

    __shared__ float sc[NSUM];          // Fourier coefficients c_k
    __shared__ float sx[ICHUNK];        // x values for this chunk
    __shared__ int   sd0[ICHUNK];       // window start per i
    __shared__ float sbasis[ICHUNK][4]; // sparse basis values
    __shared__ float spart[512];        // h-reduction

    // --- Fourier coefficients (input-independent, ~11 sinf each) ---
    if (tid < NSUM) {
        const float k = (float)(tid + 1);
        const float t = PI_F * k / A_SUP;
        float z0 = 0.5f * t;
        float c  = sinf(z0) / z0;                 // sinc(t/2)^n, n = 1
        float div = 0.5f;
        #pragma unroll
        for (int j = 1; j <= NPROD; ++j) {        // prod_{j=1..10} sinc(t/2^j)
            const float zz = t * div;
            c *= sinf(zz) / zz;
            div *= 0.5f;
        }
        sc[tid] = c;
    }

    // --- per-i window start: active d satisfy |(x - c_d)*16| <= 1.5 ---
    if (tid < ICHUNK) {
        const float xv = x[b * I_ + i0 + tid];
        sx[tid] = xv;
        const float lo = 16.0f * (xv + 1.0f) - A_SUP;   // d >= lo
        int d0 = (int)ceilf(lo);
        d0 = min(max(d0, 0), D_ - 4);
        sd0[tid] = d0;
    }
    __syncthreads();

    // --- Phase A: ICHUNK*4 series, one per thread: (i, dd) = (t>>2, t&3) ---
    if (tid < ICHUNK * 4) {
        const int i  = tid >> 2;
        const int dd = tid & 3;
        const int d  = sd0[i] + dd;
        const float z = (sx[i] - cen[d]) * comp[d];     // same op order as ref
        float s = 0.0f;
        if (fabsf(z) <= A_SUP) {
            const float th   = (PI_F / A_SUP) * z;
            const float c1   = cosf(th);
            float ckm1 = c1, ckm2 = 1.0f;
            s = 0.5f + sc[0] * c1;
            #pragma unroll 4
            for (int k = 2; k <= NSUM; ++k) {
                const float ck = 2.0f * c1 * ckm1 - ckm2;
                s += sc[k - 1] * ck;
                ckm2 = ckm1;
                ckm1 = ck;
            }
            s *= (1.0f / A_SUP);
        }
        sbasis[i][dd] = s;
    }
    __syncthreads();

    // --- Phase B: thread = (h, o); h splits the i-chunk in two ---
    const int o = tid & (O_ - 1);
    const int h = tid >> 8;                        // 0 or 1
    float acc = 0.0f;
    const int i_lo = h * (ICHUNK / 2);
    #pragma unroll 4
    for (int il = i_lo; il < i_lo + ICHUNK / 2; ++il) {
        const int d0 = sd0[il];
        const float* wp = Wt + ((((size_t)(i0 + il)) * D_ + d0) << 8) + o; // Wt[i][d0][o]
        const float b0 = sbasis[il][0], b1 = sbasis[il][1];
        const float b2 = sbasis[il][2], b3 = sbasis[il][3];
        acc += b0 * wp[0]      + b1 * wp[O_]
             + b2 * wp[2 * O_] + b3 * wp[3 * O_];
    }
    spart[tid] = acc;
    __syncthreads();
    if (tid < O_)
        atomicAdd(&y[b * O_ + tid], spart[tid] + spart[tid + O_]);
}

extern "C" void kernel_launch(void* const* d_in, const int* in_sizes, int n_in,
                              void* d_out, int out_size, void* d_ws, size_t ws_size,
                              hipStream_t stream) {
    const float* x    = (const float*)d_in[0];
    const float* W    = (const float*)d_in[1];   // (I, O, D)
    const float* comp = (const float*)d_in[2];   // (D,)
    const float* cen  = (const float*)d_in[3];   // (D,)
    float* y = (float*)d_out;                    // (B, O)

    float* Wt = (float*)d_ws;                    // I*D*O floats = 4.3 MB

    hipMemsetAsync(y, 0, (size_t)out_size * sizeof(float), stream);
    transpose_w<<<I_, 256, 0, stream>>>(W, Wt);
    kan_main<<<B_ * NCHUNK, 512, 0, stream>>>(x, Wt, comp, cen, y);
}

// Round 5
// 82.800 us; speedup vs baseline: 1.0501x; 1.0501x over previous
//
#include <hip/hip_runtime.h>
#include <hip/hip_bf16.h>
#include <math.h>

#define B_    256
#define I_    128
#define O_    256
#define D_    33
#define NSUM  100
#define NPROD 10
#define A_SUP 1.5f
#define PI_F  3.14159265358979323846f

#define ICHUNK 32                      // i's per block
#define NCHUNK (I_ / ICHUNK)           // 4 blocks per batch row

// ---------------------------------------------------------------------------
// Prep: transpose W[i][o][d] (fp32) -> Wt[i][d][o] (bf16). bf16 halves the
// working set to 2.15 MB so it is resident in each XCD's 4 MB L2 (the R3
// fp32 version was 4.3 MB -> L2 capacity thrash -> Infinity-Cache-BW bound).
// Also zeroes y (folds the memset launch away). One block per i.
// LDS reads ld[o*33+d]: stride 33 mod 32 == 1 -> conflict-free.
// ---------------------------------------------------------------------------
__global__ __launch_bounds__(256) void transpose_w(const float* __restrict__ W,
                                                   __hip_bfloat16* __restrict__ Wt,
                                                   float* __restrict__ y) {
    const int i = blockIdx.x;
    __shared__ float ld[O_ * D_];                 // 33 KiB
    const float* src = W + (size_t)i * O_ * D_;
    for (int t = threadIdx.x; t < O_ * D_; t += blockDim.x)
        ld[t] = src[t];
    // zero y: 128 blocks x 256 threads x 2 floats = 65536 = B_*O_
    {
        const int base = (i * 256 + (int)threadIdx.x) * 2;
        y[base] = 0.0f;
        y[base + 1] = 0.0f;
    }
    __syncthreads();
    __hip_bfloat16* dst = Wt + (size_t)i * D_ * O_;
    for (int t = threadIdx.x; t < D_ * O_; t += blockDim.x) {
        const int d = t >> 8;                     // t / 256
        const int o = t & (O_ - 1);               // t % 256
        dst[t] = __float2bfloat16(ld[o * D_ + d]);
    }
}

// ---------------------------------------------------------------------------
// Main: grid = B * NCHUNK. Block (b, chunk) handles ICHUNK i's for row b.
// Phase A: sparse basis (ICHUNK i x 4 d window) via Chebyshev cos recurrence.
// Phase B: partial y[b,o] over this i-chunk, coalesced bf16 reads of Wt
// (L2-resident), fp32 accumulate, one atomicAdd per o.
// ---------------------------------------------------------------------------
__global__ __launch_bounds__(512, 4) void kan_main(const float* __restrict__ x,
                                                   const __hip_bfloat16* __restrict__ Wt,
                                                   const float* __restrict__ comp,
                                                   const float* __restrict__ cen,
                                                   float* __restrict__ y) {
    const int b     = blockIdx.x >> 2;            // blockIdx.x / NCHUNK
    const int chunk = blockIdx.x & (NCHUNK - 1);
    const int i0    = chunk * ICHUNK;
    const int tid   = threadIdx.x;

    __shared__ float sc[NSUM];          // Fourier coefficients c_k
    __shared__ float sx[ICHUNK];        // x values for this chunk
    __shared__ int   sd0[ICHUNK];       // window start per i
    __shared__ float sbasis[ICHUNK][4]; // sparse basis values
    __shared__ float spart[512];        // h-reduction

    // --- Fourier coefficients (input-independent, ~11 sinf each) ---
    if (tid < NSUM) {
        const float k = (float)(tid + 1);
        const float t = PI_F * k / A_SUP;
        float z0 = 0.5f * t;
        float c  = sinf(z0) / z0;                 // sinc(t/2)^n, n = 1
        float div = 0.5f;
        #pragma unroll
        for (int j = 1; j <= NPROD; ++j) {        // prod_{j=1..10} sinc(t/2^j)
            const float zz = t * div;
            c *= sinf(zz) / zz;
            div *= 0.5f;
        }
        sc[tid] = c;
    }

    // --- per-i window start: active d satisfy |(x - c_d)*16| <= 1.5 ---
    if (tid < ICHUNK) {
        const float xv = x[b * I_ + i0 + tid];
        sx[tid] = xv;
        const float lo = 16.0f * (xv + 1.0f) - A_SUP;   // d >= lo
        int d0 = (int)ceilf(lo);
        d0 = min(max(d0, 0), D_ - 4);
        sd0[tid] = d0;
    }
    __syncthreads();

    // --- Phase A: ICHUNK*4 series, one per thread: (i, dd) = (t>>2, t&3) ---
    if (tid < ICHUNK * 4) {
        const int i  = tid >> 2;
        const int dd = tid & 3;
        const int d  = sd0[i] + dd;
        const float z = (sx[i] - cen[d]) * comp[d];     // same op order as ref
        float s = 0.0f;
        if (fabsf(z) <= A_SUP) {
            const float th   = (PI_F / A_SUP) * z;
            const float c1   = cosf(th);
            float ckm1 = c1, ckm2 = 1.0f;
            s = 0.5f + sc[0] * c1;
            #pragma unroll 4
            for (int k = 2; k <= NSUM; ++k) {
                const float ck = 2.0f * c1 * ckm1 - ckm2;
                s += sc[k - 1] * ck;
                ckm2 = ckm1;
                ckm1 = ck;
            }
            s *= (1.0f / A_SUP);
        }
        sbasis[i][dd] = s;
    }
    __syncthreads();

    // --- Phase B: thread = (h, o); h splits the i-chunk in two ---
    const int o = tid & (O_ - 1);
    const int h = tid >> 8;                        // 0 or 1
    float acc = 0.0f;
    const int i_lo = h * (ICHUNK / 2);
    #pragma unroll 4
    for (int il = i_lo; il < i_lo + ICHUNK / 2; ++il) {
        const int d0 = sd0[il];
        const __hip_bfloat16* wp =
            Wt + ((((size_t)(i0 + il)) * D_ + d0) << 8) + o;   // Wt[i][d0][o]
        const float b0 = sbasis[il][0], b1 = sbasis[il][1];
        const float b2 = sbasis[il][2], b3 = sbasis[il][3];
        acc += b0 * __bfloat162float(wp[0])
             + b1 * __bfloat162float(wp[O_])
             + b2 * __bfloat162float(wp[2 * O_])
             + b3 * __bfloat162float(wp[3 * O_]);
    }
    spart[tid] = acc;
    __syncthreads();
    if (tid < O_)
        atomicAdd(&y[b * O_ + tid], spart[tid] + spart[tid + O_]);
}

extern "C" void kernel_launch(void* const* d_in, const int* in_sizes, int n_in,
                              void* d_out, int out_size, void* d_ws, size_t ws_size,
                              hipStream_t stream) {
    const float* x    = (const float*)d_in[0];
    const float* W    = (const float*)d_in[1];   // (I, O, D)
    const float* comp = (const float*)d_in[2];   // (D,)
    const float* cen  = (const float*)d_in[3];   // (D,)
    float* y = (float*)d_out;                    // (B, O)

    __hip_bfloat16* Wt = (__hip_bfloat16*)d_ws;  // I*D*O bf16 = 2.15 MB

    transpose_w<<<I_, 256, 0, stream>>>(W, Wt, y);
    kan_main<<<B_ * NCHUNK, 512, 0, stream>>>(x, Wt, comp, cen, y);
}

// Round 8
// 82.506 us; speedup vs baseline: 1.0538x; 1.0036x over previous
//
#include <hip/hip_runtime.h>
#include <hip/hip_bf16.h>
#include <math.h>

#define B_    256
#define I_    128
#define O_    256
#define D_    33
#define NSUM  100
#define NPROD 10
#define A_SUP 1.5f
#define PI_F  3.14159265358979323846f

// d_ws layout: [ Wt: I*D*O bf16 = 2,162,688 B ][ sc: NSUM fp32 = 400 B ]
#define WT_ELEMS ((size_t)I_ * D_ * O_)

// ---------------------------------------------------------------------------
// Prep: W[i][o][d] (fp32) -> Wt[i][d][o] (bf16, 2.15 MB -> XCD-L2-resident).
// Block 0 additionally computes the 100 Fourier-series coefficients into d_ws
// (they are input-independent; computing them in every kan_main block added
// ~11 sinf of serial latency before phase A in 1024 blocks in R5).
// LDS reads ld[o*33+d]: stride 33 mod 32 == 1 -> conflict-free.
// ---------------------------------------------------------------------------
__global__ __launch_bounds__(256) void transpose_w(const float* __restrict__ W,
                                                   __hip_bfloat16* __restrict__ Wt,
                                                   float* __restrict__ scW) {
    const int i = blockIdx.x;
    __shared__ float ld[O_ * D_];                 // 33 KiB
    const float* src = W + (size_t)i * O_ * D_;
    for (int t = threadIdx.x; t < O_ * D_; t += blockDim.x)
        ld[t] = src[t];
    if (i == 0 && threadIdx.x < NSUM) {
        const float k = (float)(threadIdx.x + 1);
        const float t = PI_F * k / A_SUP;
        float z0 = 0.5f * t;
        float c  = sinf(z0) / z0;                 // sinc(t/2)^n, n = 1
        float div = 0.5f;
        #pragma unroll
        for (int j = 1; j <= NPROD; ++j) {        // prod_{j=1..10} sinc(t/2^j)
            const float zz = t * div;
            c *= sinf(zz) / zz;
            div *= 0.5f;
        }
        scW[threadIdx.x] = c;
    }
    __syncthreads();
    __hip_bfloat16* dst = Wt + (size_t)i * D_ * O_;
    for (int t = threadIdx.x; t < D_ * O_; t += blockDim.x) {
        const int d = t >> 8;                     // t / 256
        const int o = t & (O_ - 1);               // t % 256
        dst[t] = __float2bfloat16(ld[o * D_ + d]);
    }
}

// ---------------------------------------------------------------------------
// Main: one block per batch row b, 512 threads, direct stores (no atomics).
// Phase A: 128 i x 4 d sparse basis via Chebyshev cos recurrence (1 thread per
// (i,dd) series). Phase B: thread = (h in 0..3, p in 0..127) accumulates o-pair
// {2p, 2p+1} over an i-chunk of 32 via coalesced ushort2 (bf16x2) reads of the
// L2-resident Wt; LDS reduce over h; coalesced fp32 store.
// ---------------------------------------------------------------------------
__global__ __launch_bounds__(512, 2) void kan_main(const float* __restrict__ x,
                                                   const __hip_bfloat16* __restrict__ Wt,
                                                   const float* __restrict__ comp,
                                                   const float* __restrict__ cen,
                                                   const float* __restrict__ scW,
                                                   float* __restrict__ y) {
    const int b   = blockIdx.x;
    const int tid = threadIdx.x;

    __shared__ float sc[NSUM];          // Fourier coefficients
    __shared__ float sx[I_];            // x row
    __shared__ int   sd0[I_];           // window start per i
    __shared__ float sbasis[I_][4];     // sparse basis values
    __shared__ float spart[4][O_];      // h-partials, [h][o] (flat-contiguous)

    // --- stage sc + x row; compute window starts ---
    if (tid < I_) {
        const float xv = x[b * I_ + tid];
        sx[tid] = xv;
        const float lo = 16.0f * (xv + 1.0f) - A_SUP;   // active d >= lo
        int d0 = (int)ceilf(lo);
        d0 = min(max(d0, 0), D_ - 4);
        sd0[tid] = d0;
    }
    if (tid >= 384 && tid < 384 + NSUM)
        sc[tid - 384] = scW[tid - 384];
    __syncthreads();

    // --- Phase A: 512 series, one per thread: (i, dd) = (tid>>2, tid&3) ---
    {
        const int i  = tid >> 2;
        const int dd = tid & 3;
        const int d  = sd0[i] + dd;
        const float z = (sx[i] - cen[d]) * comp[d];     // same op order as ref
        float s = 0.0f;
        if (fabsf(z) <= A_SUP) {
            const float th = (PI_F / A_SUP) * z;
            const float c1 = cosf(th);
            float ckm1 = c1, ckm2 = 1.0f;
            s = 0.5f + sc[0] * c1;
            #pragma unroll 4
            for (int k = 2; k <= NSUM; ++k) {
                const float ck = 2.0f * c1 * ckm1 - ckm2;
                s += sc[k - 1] * ck;
                ckm2 = ckm1;
                ckm1 = ck;
            }
            s *= (1.0f / A_SUP);
        }
        sbasis[i][dd] = s;
    }
    __syncthreads();

    // --- Phase B: thread = (h, p); o-pair {2p, 2p+1}, i-chunk of 32 ---
    const int p = tid & 127;
    const int h = tid >> 7;                        // 0..3
    float acc0 = 0.0f, acc1 = 0.0f;
    const int i_lo = h * 32;
    #pragma unroll 4
    for (int i = i_lo; i < i_lo + 32; ++i) {
        const int d0 = sd0[i];
        const ushort2* wp = (const ushort2*)
            (Wt + ((((size_t)i) * D_ + d0) << 8)) + p;  // Wt[i][d0][2p..2p+1]
        const float b0 = sbasis[i][0], b1 = sbasis[i][1];
        const float b2 = sbasis[i][2], b3 = sbasis[i][3];
        const ushort2 w0 = wp[0];
        const ushort2 w1 = wp[O_ / 2];
        const ushort2 w2 = wp[O_];
        const ushort2 w3 = wp[3 * (O_ / 2)];
        acc0 += b0 * __bfloat162float(*(const __hip_bfloat16*)&w0.x)
              + b1 * __bfloat162float(*(const __hip_bfloat16*)&w1.x)
              + b2 * __bfloat162float(*(const __hip_bfloat16*)&w2.x)
              + b3 * __bfloat162float(*(const __hip_bfloat16*)&w3.x);
        acc1 += b0 * __bfloat162float(*(const __hip_bfloat16*)&w0.y)
              + b1 * __bfloat162float(*(const __hip_bfloat16*)&w1.y)
              + b2 * __bfloat162float(*(const __hip_bfloat16*)&w2.y)
              + b3 * __bfloat162float(*(const __hip_bfloat16*)&w3.y);
    }
    spart[h][2 * p]     = acc0;
    spart[h][2 * p + 1] = acc1;
    __syncthreads();

    // --- reduce over h and store: o == tid for tid < 256 -> coalesced ---
    if (tid < O_)
        y[b * O_ + tid] = spart[0][tid] + spart[1][tid]
                        + spart[2][tid] + spart[3][tid];
}

extern "C" void kernel_launch(void* const* d_in, const int* in_sizes, int n_in,
                              void* d_out, int out_size, void* d_ws, size_t ws_size,
                              hipStream_t stream) {
    const float* x    = (const float*)d_in[0];
    const float* W    = (const float*)d_in[1];   // (I, O, D)
    const float* comp = (const float*)d_in[2];   // (D,)
    const float* cen  = (const float*)d_in[3];   // (D,)
    float* y = (float*)d_out;                    // (B, O)

    __hip_bfloat16* Wt = (__hip_bfloat16*)d_ws;          // 2.15 MB
    float* scW = (float*)((char*)d_ws + WT_ELEMS * sizeof(__hip_bfloat16));

    transpose_w<<<I_, 256, 0, stream>>>(W, Wt, scW);
    kan_main<<<B_, 512, 0, stream>>>(x, Wt, comp, cen, scW, y);
}